// Round 11
// baseline (780.425 us; speedup 1.0000x reference)
//
#include <hip/hip_runtime.h>
#include <math.h>

#define HW 16384

using short8 = __attribute__((ext_vector_type(8))) short;
using f32x4  = __attribute__((ext_vector_type(4))) float;

__device__ __forceinline__ float bf2f(unsigned short u){
  union { unsigned int i; float f; } x; x.i = ((unsigned int)u) << 16; return x.f;
}
__device__ __forceinline__ unsigned short f2bf(float f){
  union { float f; unsigned int i; } x; x.f = f;
  return (unsigned short)((x.i + 0x7FFFu + ((x.i >> 16) & 1u)) >> 16);
}

// ---------------- weight fp32 -> bf16 ----------------
__global__ void castw_k(const float* __restrict__ in, unsigned short* __restrict__ out, int n){
  int i = blockIdx.x * 256 + threadIdx.x;
  if (i < n) out[i] = f2bf(in[i]);
}
// cast + pad K: in [M][Kin] -> out [M][Kout], zeros beyond Kin
__global__ void castw_pad_k(const float* __restrict__ in, unsigned short* __restrict__ out,
                            int M, int Kin, int Kout){
  int i = blockIdx.x * 256 + threadIdx.x;
  if (i < M * Kout){
    int m = i / Kout, k = i - m * Kout;
    out[i] = (k < Kin) ? f2bf(in[m * Kin + k]) : (unsigned short)0;
  }
}

// ---------------- time modulation: silu(t_emb) @ W^T + b ----------------
__global__ void modk(const float* __restrict__ t_emb,
                     const float* __restrict__ aw, const float* __restrict__ ab,
                     const float* __restrict__ fw, const float* __restrict__ fb,
                     float* __restrict__ mod_a, float* __restrict__ mod_f){
  int o = blockIdx.x * 128 + threadIdx.x;   // 0..383
  int b = blockIdx.y;
  const float* w  = blockIdx.z ? fw : aw;
  const float* bi = blockIdx.z ? fb : ab;
  float* outp     = blockIdx.z ? mod_f : mod_a;
  const float* te = t_emb + b * 256;
  float acc = bi[o];
  for (int k = 0; k < 256; ++k){
    float u = te[k];
    float s = u / (1.f + expf(-u));
    acc += s * w[o * 256 + k];
  }
  outp[b * 384 + o] = acc;
}

// ---------------- channel LayerNorm (ddof=1, std+eps) + modulate -> bf16 PIXEL-MAJOR --------------
// One thread per pixel: no LDS, no barrier; full 384B row per thread (no cross-wave line sharing).
__global__ __launch_bounds__(256) void lnmod_k(const float* __restrict__ x,
                                               const float* __restrict__ nw, const float* __restrict__ nb,
                                               const float* __restrict__ mod, unsigned short* __restrict__ y){
  int b = blockIdx.y;
  int p = blockIdx.x * 256 + threadIdx.x;
  const float* xb = x + (size_t)b * 192 * HW + p;
  float s = 0.f, s2 = 0.f;
  #pragma unroll 8
  for (int c = 0; c < 192; ++c){
    float v = xb[(size_t)c * HW]; s += v; s2 += v * v;
  }
  float mean = s * (1.f / 192.f);
  float var  = (s2 - s * mean) * (1.f / 191.f);
  float rinv = 1.f / (sqrtf(fmaxf(var, 0.f)) + 1e-6f);
  const float* mo = mod + b * 384;
  unsigned short* yb = y + ((size_t)b * HW + p) * 192;
  #pragma unroll
  for (int c8 = 0; c8 < 24; ++c8){
    unsigned short ob[8];
    #pragma unroll
    for (int j = 0; j < 8; ++j){
      int c = c8 * 8 + j;
      float v = xb[(size_t)c * HW];
      float ln = nw[c] * ((v - mean) * rinv) + nb[c];
      ob[j] = f2bf(ln * (1.f + mo[c]) + mo[192 + c]);
    }
    *(uint4*)(yb + c8 * 8) = *(const uint4*)ob;
  }
}

// ---------------- bf16 MFMA GEMM: dbuf single-barrier + LDS-transposed coalesced epilogue ---------
// out[b][m][n] = W[m][k] @ Act[b][n][k] + bias (+resid). K mult of 32.
// BM=64, BN=256, BK=32, 4 waves. Grid (nMb, 64, 4) m-fastest (round-0 order: byte-exact writes).
// K-loop: issue next-tile loads -> ds_read+MFMA -> ds_write next -> ONE barrier.
__global__ __launch_bounds__(256, 2) void gemm_tn2(const unsigned short* __restrict__ A,
                                                   const unsigned short* __restrict__ Bact,
                                                   const float* __restrict__ bias,
                                                   const float* resid, void* outp,
                                                   int M, int K, int ofp32){
  const int N = HW;
  __shared__ unsigned short SMEM[20480];     // 40 KB: As dbuf 8KB | Bs dbuf 32KB; reused by epilogue
  const int m0 = blockIdx.x * 64;
  const int n0 = blockIdx.y * 256;
  const int bz = blockIdx.z;
  const unsigned short* Bp = Bact + (size_t)bz * N * K;
  const int t = threadIdx.x;
  const int w = t >> 6, lane = t & 63;
  const int l16 = lane & 15, quad = lane >> 4;

  // staging geometry: phys slot = logical slot ^ ((row ^ row>>2) & 3)
  const int arow = t >> 2, akc = t & 3;
  int gm = m0 + arow; if (gm > M - 1) gm = M - 1;     // clamp; masked in epilogue
  const unsigned short* agp = A + (size_t)gm * K + akc * 8;
  const int aoff = arow * 32 + ((akc ^ ((arow ^ (arow >> 2)) & 3)) * 8);
  const int brow = t >> 2, bkc = t & 3;
  const unsigned short* bgp = Bp + (size_t)(n0 + brow) * K + bkc * 8;
  const int bslot = (bkc ^ ((brow ^ (brow >> 2)) & 3)) * 8;   // row+64i keeps bits0-3 -> same

  f32x4 acc[4][4];
  #pragma unroll
  for (int i = 0; i < 4; ++i)
    #pragma unroll
    for (int j = 0; j < 4; ++j) acc[i][j] = (f32x4){0.f, 0.f, 0.f, 0.f};

  const int kTiles = K >> 5;
  {  // prologue: stage tile 0 into buf 0
    uint4 va = *(const uint4*)agp;
    *(uint4*)&SMEM[aoff] = va;
    #pragma unroll
    for (int i = 0; i < 4; ++i){
      uint4 vb = *(const uint4*)(bgp + (size_t)(64 * i) * K);
      *(uint4*)&SMEM[4096 + (brow + 64 * i) * 32 + bslot] = vb;
    }
  }
  __syncthreads();

  const int fs = (quad ^ ((l16 ^ (l16 >> 2)) & 3)) * 8;   // fragment phys slot (2-way banks)
  for (int kt = 0; kt < kTiles; ++kt){
    const int cur = kt & 1;
    const bool more = (kt + 1 < kTiles);
    uint4 va; uint4 vb[4];
    if (more){
      const int k0 = (kt + 1) * 32;
      va = *(const uint4*)(agp + k0);
      #pragma unroll
      for (int i = 0; i < 4; ++i)
        vb[i] = *(const uint4*)(bgp + (size_t)(64 * i) * K + k0);
    }
    const int abase = cur * 2048;
    const int bbase = 4096 + cur * 8192;
    short8 af[4], bfr[4];
    #pragma unroll
    for (int mt = 0; mt < 4; ++mt)
      af[mt] = *(const short8*)&SMEM[abase + (mt * 16 + l16) * 32 + fs];
    #pragma unroll
    for (int nt = 0; nt < 4; ++nt)
      bfr[nt] = *(const short8*)&SMEM[bbase + (w * 64 + nt * 16 + l16) * 32 + fs];
    #pragma unroll
    for (int nt = 0; nt < 4; ++nt)
      #pragma unroll
      for (int mt = 0; mt < 4; ++mt)
        acc[mt][nt] = __builtin_amdgcn_mfma_f32_16x16x32_bf16(af[mt], bfr[nt], acc[mt][nt], 0, 0, 0);
    if (more){
      const int nabase = (cur ^ 1) * 2048;
      const int nbbase = 4096 + (cur ^ 1) * 8192;
      *(uint4*)&SMEM[nabase + aoff] = va;
      #pragma unroll
      for (int i = 0; i < 4; ++i)
        *(uint4*)&SMEM[nbbase + (brow + 64 * i) * 32 + bslot] = vb[i];
    }
    __syncthreads();
  }

  // ---- epilogue: LDS transpose -> coalesced global I/O ----
  if (!ofp32){
    // bf16 out (qkv, f_c1). T: [64][264] shorts (16896 <= 20480)
    unsigned short* T = SMEM;
    #pragma unroll
    for (int mt = 0; mt < 4; ++mt)
      #pragma unroll
      for (int nt = 0; nt < 4; ++nt)
        #pragma unroll
        for (int r = 0; r < 4; ++r){
          int ml = mt * 16 + quad * 4 + r;
          int bm = m0 + ml; if (bm > M - 1) bm = M - 1;
          T[ml * 264 + w * 64 + nt * 16 + l16] = f2bf(acc[mt][nt][r] + bias[bm]);
        }
    __syncthreads();
    unsigned short* ob = (unsigned short*)outp + (size_t)bz * M * N;
    #pragma unroll
    for (int i = 0; i < 8; ++i){
      int c = t + 256 * i;
      int row = c >> 5, col = (c & 31) * 8;   // 32 chunks x 64 rows
      if (m0 + row < M)
        *(uint4*)(ob + (size_t)(m0 + row) * N + n0 + col) = *(const uint4*)&T[row * 264 + col];
    }
  } else {
    // fp32 out (proj, f_c2) + coalesced resid read. T: [32][260] floats (33.3KB), two halves.
    float* T = (float*)&SMEM[0];
    float* ob = (float*)outp + (size_t)bz * M * N;
    const float* rb = resid ? resid + (size_t)bz * M * N : nullptr;
    #pragma unroll
    for (int half = 0; half < 2; ++half){
      #pragma unroll
      for (int mt = 0; mt < 2; ++mt)
        #pragma unroll
        for (int nt = 0; nt < 4; ++nt)
          #pragma unroll
          for (int r = 0; r < 4; ++r){
            int ml = mt * 16 + quad * 4 + r;            // 0..31 within half
            T[ml * 260 + w * 64 + nt * 16 + l16] = acc[half * 2 + mt][nt][r];
          }
      __syncthreads();
      #pragma unroll
      for (int i = 0; i < 8; ++i){
        int c = t + 256 * i;
        int row = c >> 6, col = (c & 63) * 4;           // 64 chunks x 32 rows
        int m = m0 + half * 32 + row;
        if (m < M){
          size_t idx = (size_t)m * N + n0 + col;
          f32x4 v = *(const f32x4*)&T[row * 260 + col];
          float bv = bias[m];
          v[0] += bv; v[1] += bv; v[2] += bv; v[3] += bv;
          if (rb){
            v[0] += rb[idx]; v[1] += rb[idx + 1]; v[2] += rb[idx + 2]; v[3] += rb[idx + 3];
          }
          *(f32x4*)&ob[idx] = v;
        }
      }
      __syncthreads();
    }
  }
}

// ---------------- depthwise 3x3 (SAME) + bias + fused q/k sum-of-squares ----------------
__global__ __launch_bounds__(256) void dw3_k(const unsigned short* __restrict__ in,
                                             const float* __restrict__ w, const float* __restrict__ bias,
                                             unsigned short* __restrict__ out, int C,
                                             float* __restrict__ qn, float* __restrict__ kn){
  __shared__ unsigned short tile[66 * 128];
  __shared__ float red[4];
  int zc = blockIdx.y;
  int b = zc / C, c = zc - b * C;
  int r0 = blockIdx.x * 64;
  const unsigned short* im = in + ((size_t)(b * C + c)) * HW;
  unsigned short* om = out + ((size_t)(b * C + c)) * HW;
  int t = threadIdx.x;
  #pragma unroll
  for (int i = 0; i < 5; ++i){
    int idx = t + 256 * i;
    if (idx < 1056){
      int lr = idx >> 4, lc = (idx & 15) * 8;
      int gr = r0 - 1 + lr;
      uint4 v = {0u, 0u, 0u, 0u};
      if ((unsigned)gr < 128u) v = *(const uint4*)(im + gr * 128 + lc);
      *(uint4*)&tile[lr * 128 + lc] = v;
    }
  }
  __syncthreads();
  const float* wc = w + c * 9;
  float W[9];
  #pragma unroll
  for (int i = 0; i < 9; ++i) W[i] = wc[i];
  float bs = bias[c];
  float ssq = 0.f;
  #pragma unroll
  for (int i = 0; i < 4; ++i){
    int seg = t + 256 * i;
    int orow = seg >> 4, sc = (seg & 15) * 8;
    float acc[8];
    #pragma unroll
    for (int j = 0; j < 8; ++j) acc[j] = bs;
    #pragma unroll
    for (int rr = 0; rr < 3; ++rr){
      const unsigned short* rp = &tile[(orow + rr) * 128 + sc];
      float v[10];
      v[0] = (sc > 0) ? bf2f(rp[-1]) : 0.f;
      uint4 m = *(const uint4*)rp;
      const unsigned short* mu = (const unsigned short*)&m;
      #pragma unroll
      for (int j = 0; j < 8; ++j) v[j + 1] = bf2f(mu[j]);
      v[9] = (sc < 120) ? bf2f(rp[8]) : 0.f;
      float wa = W[rr * 3], wb = W[rr * 3 + 1], wd = W[rr * 3 + 2];
      #pragma unroll
      for (int j = 0; j < 8; ++j) acc[j] += wa * v[j] + wb * v[j + 1] + wd * v[j + 2];
    }
    unsigned short ob[8];
    #pragma unroll
    for (int j = 0; j < 8; ++j){
      ob[j] = f2bf(acc[j]);
      float q = bf2f(ob[j]);
      ssq += q * q;
    }
    *(uint4*)(om + (r0 + orow) * 128 + sc) = *(uint4*)ob;
  }
  if (c < 384){   // block-uniform branch
    #pragma unroll
    for (int off = 32; off; off >>= 1) ssq += __shfl_down(ssq, off);
    if ((t & 63) == 0) red[t >> 6] = ssq;
    __syncthreads();
    if (t == 0){
      float s = red[0] + red[1] + red[2] + red[3];
      float* dst = (c < 192) ? (qn + b * 192 + c) : (kn + b * 192 + c - 192);
      atomicAdd(dst, s);
    }
  }
}

// ---------------- GDFN: g = dw(h[0:510]) * dw(h[510:1020]), channel-major out ----------------
__global__ __launch_bounds__(256) void dwgate_k(const unsigned short* __restrict__ h,
                                                const float* __restrict__ w, const float* __restrict__ bias,
                                                unsigned short* __restrict__ g){
  __shared__ unsigned short tile[2 * 66 * 128];
  int zc = blockIdx.y;
  int b = zc / 510, j = zc - b * 510;
  int r0 = blockIdx.x * 64;
  const unsigned short* im1 = h + ((size_t)(b * 1020 + j)) * HW;
  const unsigned short* im2 = h + ((size_t)(b * 1020 + 510 + j)) * HW;
  int t = threadIdx.x;
  #pragma unroll
  for (int i = 0; i < 9; ++i){
    int idx = t + 256 * i;
    if (idx < 2112){
      int img = (idx >= 1056) ? 1 : 0;
      int li = idx - img * 1056;
      int lr = li >> 4, lc = (li & 15) * 8;
      int gr = r0 - 1 + lr;
      uint4 v = {0u, 0u, 0u, 0u};
      const unsigned short* im = img ? im2 : im1;
      if ((unsigned)gr < 128u) v = *(const uint4*)(im + gr * 128 + lc);
      *(uint4*)&tile[img * 8448 + lr * 128 + lc] = v;
    }
  }
  __syncthreads();
  float W1[9], W2[9];
  #pragma unroll
  for (int i = 0; i < 9; ++i){ W1[i] = w[j * 9 + i]; W2[i] = w[(510 + j) * 9 + i]; }
  float b1 = bias[j], b2 = bias[510 + j];
  unsigned short* gm = g + ((size_t)(b * 510 + j)) * HW;
  #pragma unroll
  for (int i = 0; i < 4; ++i){
    int seg = t + 256 * i;
    int orow = seg >> 4, sc = (seg & 15) * 8;
    float a1[8], a2[8];
    #pragma unroll
    for (int q = 0; q < 8; ++q){ a1[q] = b1; a2[q] = b2; }
    #pragma unroll
    for (int rr = 0; rr < 3; ++rr){
      #pragma unroll
      for (int img = 0; img < 2; ++img){
        const unsigned short* rp = &tile[img * 8448 + (orow + rr) * 128 + sc];
        float v[10];
        v[0] = (sc > 0) ? bf2f(rp[-1]) : 0.f;
        uint4 m = *(const uint4*)rp;
        const unsigned short* mu = (const unsigned short*)&m;
        #pragma unroll
        for (int q = 0; q < 8; ++q) v[q + 1] = bf2f(mu[q]);
        v[9] = (sc < 120) ? bf2f(rp[8]) : 0.f;
        const float* ww = img ? W2 : W1;
        float* aa = img ? a2 : a1;
        float wa = ww[rr * 3], wb = ww[rr * 3 + 1], wd = ww[rr * 3 + 2];
        #pragma unroll
        for (int q = 0; q < 8; ++q) aa[q] += wa * v[q] + wb * v[q + 1] + wd * v[q + 2];
      }
    }
    unsigned short ob[8];
    #pragma unroll
    for (int q = 0; q < 8; ++q) ob[q] = f2bf(a1[q] * a2[q]);
    *(uint4*)(gm + (r0 + orow) * 128 + sc) = *(uint4*)ob;
  }
}

// ---------------- transpose [C][HW] -> [HW][Kout] bf16, zero-pad channels >= C ----------------
__global__ __launch_bounds__(256) void tr_k(const unsigned short* __restrict__ in,
                                            unsigned short* __restrict__ out, int C, int Kout){
  __shared__ unsigned short tile[64 * 72];
  int b = blockIdx.z;
  int p0 = blockIdx.x * 64, c0 = blockIdx.y * 64;
  int t = threadIdx.x;
  #pragma unroll
  for (int i = 0; i < 2; ++i){
    int id = t + 256 * i;               // 512 chunks: 64ch x 8
    int ch = id >> 3, pc = (id & 7) * 8;
    uint4 v = {0u, 0u, 0u, 0u};
    if (c0 + ch < C) v = *(const uint4*)(in + ((size_t)(b * C + c0 + ch)) * HW + p0 + pc);
    const unsigned short* u = (const unsigned short*)&v;
    #pragma unroll
    for (int j = 0; j < 8; ++j) tile[(pc + j) * 72 + ch] = u[j];
  }
  __syncthreads();
  #pragma unroll
  for (int i = 0; i < 2; ++i){
    int id = t + 256 * i;               // 512 chunks: 64px x 8
    int px = id >> 3, cc = (id & 7) * 8;
    *(uint4*)(out + ((size_t)b * HW + p0 + px) * Kout + c0 + cc) = *(const uint4*)&tile[px * 72 + cc];
  }
}

// ---------------- QK^T via MFMA, K-split partials. grid (32 ksplit, 32 bh), 1 wave ----------------
__global__ __launch_bounds__(64) void qk_k(const unsigned short* __restrict__ qkv_dw, float* __restrict__ part){
  int bh = blockIdx.y; int b = bh >> 3, h = bh & 7;
  int ks = blockIdx.x;
  int lane = threadIdx.x;
  int l16 = lane & 15, quad = lane >> 4;
  const unsigned short* qb = qkv_dw + ((size_t)b * 576 + h * 24) * HW;
  const unsigned short* kb = qkv_dw + ((size_t)b * 576 + 192 + h * 24) * HW;
  f32x4 z = {0.f, 0.f, 0.f, 0.f};
  f32x4 a00 = z, a01 = z, a10 = z, a11 = z;
  for (int st = 0; st < 16; ++st){
    int k0 = ks * 512 + st * 32 + quad * 8;
    short8 qa0 = *(const short8*)(qb + (size_t)l16 * HW + k0);
    short8 qa1 = *(const short8*)(qb + (size_t)(l16 + 16) * HW + k0);
    short8 kb0 = *(const short8*)(kb + (size_t)l16 * HW + k0);
    short8 kb1 = *(const short8*)(kb + (size_t)(l16 + 16) * HW + k0);
    a00 = __builtin_amdgcn_mfma_f32_16x16x32_bf16(qa0, kb0, a00, 0, 0, 0);
    a01 = __builtin_amdgcn_mfma_f32_16x16x32_bf16(qa0, kb1, a01, 0, 0, 0);
    a10 = __builtin_amdgcn_mfma_f32_16x16x32_bf16(qa1, kb0, a10, 0, 0, 0);
    a11 = __builtin_amdgcn_mfma_f32_16x16x32_bf16(qa1, kb1, a11, 0, 0, 0);
  }
  float* pp = part + ((size_t)bh * 32 + ks) * 576;
  #pragma unroll
  for (int r = 0; r < 4; ++r){
    int c0 = quad * 4 + r, c1 = 16 + quad * 4 + r;
    int d0 = l16, d1 = 16 + l16;
    if (c0 < 24 && d0 < 24) pp[c0 * 24 + d0] = a00[r];
    if (c0 < 24 && d1 < 24) pp[c0 * 24 + d1] = a01[r];
    if (c1 < 24 && d0 < 24) pp[c1 * 24 + d0] = a10[r];
    if (c1 < 24 && d1 < 24) pp[c1 * 24 + d1] = a11[r];
  }
}

// ---------------- reduce partials, scale by temp/(|q||k|), softmax over d ----------------
__global__ void softmax_k(const float* __restrict__ part, const float* __restrict__ qn,
                          const float* __restrict__ kn, const float* __restrict__ temp,
                          float* __restrict__ attn){
  int bh = blockIdx.x; int b = bh >> 3, h = bh & 7;
  int c = threadIdx.x;
  if (c >= 24) return;
  float tmp = temp[h];
  float qv = fmaxf(sqrtf(qn[b * 192 + h * 24 + c]), 1e-12f);
  float row[24];
  #pragma unroll
  for (int d = 0; d < 24; ++d){
    float s = 0.f;
    for (int sp = 0; sp < 32; ++sp) s += part[((size_t)bh * 32 + sp) * 576 + c * 24 + d];
    float kv = fmaxf(sqrtf(kn[b * 192 + h * 24 + d]), 1e-12f);
    row[d] = s * tmp / (qv * kv);
  }
  float mx = row[0];
  #pragma unroll
  for (int d = 1; d < 24; ++d) mx = fmaxf(mx, row[d]);
  float sum = 0.f;
  #pragma unroll
  for (int d = 0; d < 24; ++d){ row[d] = expf(row[d] - mx); sum += row[d]; }
  float inv = 1.f / sum;
  #pragma unroll
  for (int d = 0; d < 24; ++d) attn[(size_t)bh * 576 + c * 24 + d] = row[d] * inv;
}

// ---------------- out[p][c] = sum_d attn[c][d] * v[d][p]  (PIXEL-MAJOR out) ----------------
__global__ __launch_bounds__(256) void av_k(const float* __restrict__ attn,
                                            const unsigned short* __restrict__ qkv_dw,
                                            unsigned short* __restrict__ o){
  int bh = blockIdx.y; int b = bh >> 3, h = bh & 7;
  __shared__ float As[576];
  int t = threadIdx.x;
  for (int i = t; i < 576; i += 256) As[i] = attn[(size_t)bh * 576 + i];
  __syncthreads();
  int p = blockIdx.x * 256 + t;
  const unsigned short* vb = qkv_dw + ((size_t)b * 576 + 384 + h * 24) * HW + p;
  float acc[24];
  #pragma unroll
  for (int c = 0; c < 24; ++c) acc[c] = 0.f;
  #pragma unroll
  for (int d = 0; d < 24; ++d){
    float vv = bf2f(vb[(size_t)d * HW]);
    #pragma unroll
    for (int c = 0; c < 24; ++c) acc[c] += As[c * 24 + d] * vv;
  }
  unsigned short ob[24];
  #pragma unroll
  for (int c = 0; c < 24; ++c) ob[c] = f2bf(acc[c]);
  unsigned short* op = o + ((size_t)b * HW + p) * 192 + h * 24;
  #pragma unroll
  for (int i = 0; i < 3; ++i) *(uint4*)(op + i * 8) = *(const uint4*)(ob + i * 8);
}

extern "C" void kernel_launch(void* const* d_in, const int* in_sizes, int n_in,
                              void* d_out, int out_size, void* d_ws, size_t ws_size,
                              hipStream_t stream){
  (void)in_sizes; (void)n_in; (void)out_size; (void)ws_size;
  const float* x        = (const float*)d_in[0];
  const float* t_emb    = (const float*)d_in[1];
  const float* n1_w     = (const float*)d_in[2];
  const float* n1_b     = (const float*)d_in[3];
  const float* temp     = (const float*)d_in[4];
  const float* a_qkv_w  = (const float*)d_in[5];
  const float* a_qkv_b  = (const float*)d_in[6];
  const float* a_dw_w   = (const float*)d_in[7];
  const float* a_dw_b   = (const float*)d_in[8];
  const float* a_proj_w = (const float*)d_in[9];
  const float* a_proj_b = (const float*)d_in[10];
  const float* a_t_w    = (const float*)d_in[11];
  const float* a_t_b    = (const float*)d_in[12];
  const float* n2_w     = (const float*)d_in[13];
  const float* n2_b     = (const float*)d_in[14];
  const float* f_c1_w   = (const float*)d_in[15];
  const float* f_c1_b   = (const float*)d_in[16];
  const float* f_dw_w   = (const float*)d_in[17];
  const float* f_dw_b   = (const float*)d_in[18];
  const float* f_c2_w   = (const float*)d_in[19];
  const float* f_c2_b   = (const float*)d_in[20];
  const float* f_t_w    = (const float*)d_in[21];
  const float* f_t_b    = (const float*)d_in[22];
  float* out = (float*)d_out;
  char* ws = (char*)d_ws;

  // workspace layout (~229 MB, phase-overlapped)
  unsigned short* y_buf = (unsigned short*)(ws + 0);          // [b][p][192] 25.2MB
  unsigned short* qkv   = (unsigned short*)(ws + 25165824);   // [b][576][HW] 75.5MB (stage A)
  unsigned short* hbuf  = (unsigned short*)(ws + 25165824);   // [b][1020][HW] 133.7MB (stage B)
  unsigned short* gbufT = (unsigned short*)(ws + 25165824);   // [b][p][512] 67.1MB (after dwgate)
  unsigned short* qkvd  = (unsigned short*)(ws + 100663296);  // [b][576][HW] 75.5MB
  unsigned short* obuf  = (unsigned short*)(ws + 176160768);  // [b][p][192] 25.2MB
  unsigned short* gbuf  = (unsigned short*)(ws + 158859264);  // [b][510][HW] 66.8MB
  const size_t S = 225705984;
  float* mod_a = (float*)(ws + S);
  float* mod_f = (float*)(ws + S + 8192);
  float* qn    = (float*)(ws + S + 16384);
  float* kn    = (float*)(ws + S + 20480);
  float* part  = (float*)(ws + S + 24576);        // 2359296
  float* attn  = (float*)(ws + S + 2383872);      // 73728
  unsigned short* Wq  = (unsigned short*)(ws + S + 2457600);  // 576x192
  unsigned short* Wp  = (unsigned short*)(ws + S + 2678784);  // 192x192
  unsigned short* W1  = (unsigned short*)(ws + S + 2752512);  // 1020x192
  unsigned short* W2p = (unsigned short*)(ws + S + 3144192);  // 192x512 (padded)

  castw_k<<<dim3((110592 + 255) / 256), 256, 0, stream>>>(a_qkv_w, Wq, 110592);
  castw_k<<<dim3((36864 + 255) / 256), 256, 0, stream>>>(a_proj_w, Wp, 36864);
  castw_k<<<dim3((195840 + 255) / 256), 256, 0, stream>>>(f_c1_w, W1, 195840);
  castw_pad_k<<<dim3((98304 + 255) / 256), 256, 0, stream>>>(f_c2_w, W2p, 192, 510, 512);
  modk<<<dim3(3, 4, 2), 128, 0, stream>>>(t_emb, a_t_w, a_t_b, f_t_w, f_t_b, mod_a, mod_f);
  (void)hipMemsetAsync(qn, 0, 2 * 768 * sizeof(float), stream);  // qn+kn contiguous

  // ---- MDTA branch ----
  lnmod_k<<<dim3(64, 4), 256, 0, stream>>>(x, n1_w, n1_b, mod_a, y_buf);
  gemm_tn2<<<dim3(9, 64, 4), 256, 0, stream>>>(Wq, y_buf, a_qkv_b, nullptr, qkv, 576, 192, 0);
  dw3_k<<<dim3(2, 2304), 256, 0, stream>>>(qkv, a_dw_w, a_dw_b, qkvd, 576, qn, kn);
  qk_k<<<dim3(32, 32), 64, 0, stream>>>(qkvd, part);
  softmax_k<<<32, 64, 0, stream>>>(part, qn, kn, temp, attn);
  av_k<<<dim3(64, 32), 256, 0, stream>>>(attn, qkvd, obuf);
  gemm_tn2<<<dim3(3, 64, 4), 256, 0, stream>>>(Wp, obuf, a_proj_b, x, out, 192, 192, 1); // out = x1

  // ---- GDFN branch ----
  lnmod_k<<<dim3(64, 4), 256, 0, stream>>>(out, n2_w, n2_b, mod_f, y_buf);
  gemm_tn2<<<dim3(16, 64, 4), 256, 0, stream>>>(W1, y_buf, f_c1_b, nullptr, hbuf, 1020, 192, 0);
  dwgate_k<<<dim3(2, 2040), 256, 0, stream>>>(hbuf, f_dw_w, f_dw_b, gbuf);
  tr_k<<<dim3(256, 8, 4), 256, 0, stream>>>(gbuf, gbufT, 510, 512);
  gemm_tn2<<<dim3(3, 64, 4), 256, 0, stream>>>(W2p, gbufT, f_c2_b, out, out, 192, 512, 1);
}

// Round 12
// 770.854 us; speedup vs baseline: 1.0124x; 1.0124x over previous
//
#include <hip/hip_runtime.h>
#include <math.h>

#define HW 16384

using short8 = __attribute__((ext_vector_type(8))) short;
using f32x4  = __attribute__((ext_vector_type(4))) float;

__device__ __forceinline__ float bf2f(unsigned short u){
  union { unsigned int i; float f; } x; x.i = ((unsigned int)u) << 16; return x.f;
}
__device__ __forceinline__ unsigned short f2bf(float f){
  union { float f; unsigned int i; } x; x.f = f;
  return (unsigned short)((x.i + 0x7FFFu + ((x.i >> 16) & 1u)) >> 16);
}

// ---------------- weight fp32 -> bf16 ----------------
__global__ void castw_k(const float* __restrict__ in, unsigned short* __restrict__ out, int n){
  int i = blockIdx.x * 256 + threadIdx.x;
  if (i < n) out[i] = f2bf(in[i]);
}
// cast + pad K: in [M][Kin] -> out [M][Kout], zeros beyond Kin
__global__ void castw_pad_k(const float* __restrict__ in, unsigned short* __restrict__ out,
                            int M, int Kin, int Kout){
  int i = blockIdx.x * 256 + threadIdx.x;
  if (i < M * Kout){
    int m = i / Kout, k = i - m * Kout;
    out[i] = (k < Kin) ? f2bf(in[m * Kin + k]) : (unsigned short)0;
  }
}

// ---------------- time modulation: silu(t_emb) @ W^T + b ----------------
__global__ void modk(const float* __restrict__ t_emb,
                     const float* __restrict__ aw, const float* __restrict__ ab,
                     const float* __restrict__ fw, const float* __restrict__ fb,
                     float* __restrict__ mod_a, float* __restrict__ mod_f){
  int o = blockIdx.x * 128 + threadIdx.x;   // 0..383
  int b = blockIdx.y;
  const float* w  = blockIdx.z ? fw : aw;
  const float* bi = blockIdx.z ? fb : ab;
  float* outp     = blockIdx.z ? mod_f : mod_a;
  const float* te = t_emb + b * 256;
  float acc = bi[o];
  for (int k = 0; k < 256; ++k){
    float u = te[k];
    float s = u / (1.f + expf(-u));
    acc += s * w[o * 256 + k];
  }
  outp[b * 384 + o] = acc;
}

// ---------------- channel LayerNorm (ddof=1, std+eps) + modulate -> bf16 PIXEL-MAJOR --------------
// One thread per pixel: no LDS, no barrier; full 384B row per thread.
__global__ __launch_bounds__(256) void lnmod_k(const float* __restrict__ x,
                                               const float* __restrict__ nw, const float* __restrict__ nb,
                                               const float* __restrict__ mod, unsigned short* __restrict__ y){
  int b = blockIdx.y;
  int p = blockIdx.x * 256 + threadIdx.x;
  const float* xb = x + (size_t)b * 192 * HW + p;
  float s = 0.f, s2 = 0.f;
  #pragma unroll 8
  for (int c = 0; c < 192; ++c){
    float v = xb[(size_t)c * HW]; s += v; s2 += v * v;
  }
  float mean = s * (1.f / 192.f);
  float var  = (s2 - s * mean) * (1.f / 191.f);
  float rinv = 1.f / (sqrtf(fmaxf(var, 0.f)) + 1e-6f);
  const float* mo = mod + b * 384;
  unsigned short* yb = y + ((size_t)b * HW + p) * 192;
  #pragma unroll
  for (int c8 = 0; c8 < 24; ++c8){
    unsigned short ob[8];
    #pragma unroll
    for (int j = 0; j < 8; ++j){
      int c = c8 * 8 + j;
      float v = xb[(size_t)c * HW];
      float ln = nw[c] * ((v - mean) * rinv) + nb[c];
      ob[j] = f2bf(ln * (1.f + mo[c]) + mo[192 + c]);
    }
    *(uint4*)(yb + c8 * 8) = *(const uint4*)ob;
  }
}

// ---------------- bf16 MFMA GEMM: BM=256 x BN=64 (act-traffic-minimal), dbuf single-barrier -------
// out[b][m][n] = W[m][k] @ Act[b][n][k] + bias (+resid). K mult of 32.
// Weights are L2-resident (<=400KB) -> cheap to re-read; act is the HBM stream, so maximize BM:
// act logical reads drop 16x->4x (f_c1), 3x (qkv), 1x (proj/f_c2).
// 4 waves: wave w owns m rows [w*64, w*64+64) x all 64 n. LDS 40KB: A dbuf 2x16KB, B dbuf 2x4KB.
// K-loop: issue next-tile loads -> ds_read+MFMA -> ds_write next -> ONE barrier.
// Epilogue: LDS transpose (padded) -> coalesced row stores (+coalesced resid reads).
__global__ __launch_bounds__(256, 2) void gemm_tn2(const unsigned short* __restrict__ A,
                                                   const unsigned short* __restrict__ Bact,
                                                   const float* __restrict__ bias,
                                                   const float* resid, void* outp,
                                                   int M, int K, int ofp32){
  const int N = HW;
  __shared__ unsigned short SMEM[20480];   // As dbuf at 0 / 8192 (shorts); Bs dbuf at 16384 / 18432
  const int m0 = blockIdx.x * 256;
  const int n0 = blockIdx.y * 64;
  const int bz = blockIdx.z;
  const unsigned short* Bp = Bact + (size_t)bz * N * K;
  const int t = threadIdx.x;
  const int w = t >> 6, lane = t & 63;
  const int l16 = lane & 15, quad = lane >> 4;

  // staging geometry: phys slot = logical slot ^ ((row ^ row>>2) & 3)
  const int arow = t >> 2, akc = t & 3;    // A: 4 chunks/thread, rows arow + 64*i
  const unsigned short* agp[4];
  #pragma unroll
  for (int i = 0; i < 4; ++i){
    int gm = m0 + arow + 64 * i; if (gm > M - 1) gm = M - 1;   // clamp; masked in epilogue
    agp[i] = A + (size_t)gm * K + akc * 8;
  }
  const int aoff = arow * 32 + ((akc ^ ((arow ^ (arow >> 2)) & 3)) * 8);  // +i*2048 per i
  const int brow = t >> 2, bkc = t & 3;    // B: 1 chunk/thread (64 rows x 4 kc)
  const unsigned short* bgp = Bp + (size_t)(n0 + brow) * K + bkc * 8;
  const int boff = brow * 32 + ((bkc ^ ((brow ^ (brow >> 2)) & 3)) * 8);

  f32x4 acc[4][4];
  #pragma unroll
  for (int i = 0; i < 4; ++i)
    #pragma unroll
    for (int j = 0; j < 4; ++j) acc[i][j] = (f32x4){0.f, 0.f, 0.f, 0.f};

  const int kTiles = K >> 5;
  {  // prologue: stage tile 0 into buf 0
    #pragma unroll
    for (int i = 0; i < 4; ++i)
      *(uint4*)&SMEM[i * 2048 + aoff] = *(const uint4*)agp[i];
    *(uint4*)&SMEM[16384 + boff] = *(const uint4*)bgp;
  }
  __syncthreads();

  const int fs = (quad ^ ((l16 ^ (l16 >> 2)) & 3)) * 8;   // fragment phys slot (2-way banks)
  for (int kt = 0; kt < kTiles; ++kt){
    const int cur = kt & 1;
    const bool more = (kt + 1 < kTiles);
    uint4 va[4]; uint4 vb;
    if (more){
      const int k0 = (kt + 1) * 32;
      #pragma unroll
      for (int i = 0; i < 4; ++i) va[i] = *(const uint4*)(agp[i] + k0);
      vb = *(const uint4*)(bgp + k0);
    }
    const int abase = cur * 8192;
    const int bbase = 16384 + cur * 2048;
    short8 af[4], bfr[4];
    #pragma unroll
    for (int mt = 0; mt < 4; ++mt)
      af[mt] = *(const short8*)&SMEM[abase + (w * 64 + mt * 16 + l16) * 32 + fs];
    #pragma unroll
    for (int nt = 0; nt < 4; ++nt)
      bfr[nt] = *(const short8*)&SMEM[bbase + (nt * 16 + l16) * 32 + fs];
    #pragma unroll
    for (int nt = 0; nt < 4; ++nt)
      #pragma unroll
      for (int mt = 0; mt < 4; ++mt)
        acc[mt][nt] = __builtin_amdgcn_mfma_f32_16x16x32_bf16(af[mt], bfr[nt], acc[mt][nt], 0, 0, 0);
    if (more){
      const int nabase = (cur ^ 1) * 8192;
      const int nbbase = 16384 + (cur ^ 1) * 2048;
      #pragma unroll
      for (int i = 0; i < 4; ++i)
        *(uint4*)&SMEM[nabase + i * 2048 + aoff] = va[i];
      *(uint4*)&SMEM[nbbase + boff] = vb;
    }
    __syncthreads();
  }

  // ---- epilogue: LDS transpose -> coalesced global I/O ----
  if (!ofp32){
    // bf16 out (qkv, f_c1). T: [256][72] shorts (18432 <= 20480)
    unsigned short* T = SMEM;
    #pragma unroll
    for (int mt = 0; mt < 4; ++mt)
      #pragma unroll
      for (int nt = 0; nt < 4; ++nt)
        #pragma unroll
        for (int r = 0; r < 4; ++r){
          int ml = w * 64 + mt * 16 + quad * 4 + r;
          int bm = m0 + ml; if (bm > M - 1) bm = M - 1;
          T[ml * 72 + nt * 16 + l16] = f2bf(acc[mt][nt][r] + bias[bm]);
        }
    __syncthreads();
    unsigned short* ob = (unsigned short*)outp + (size_t)bz * M * N;
    #pragma unroll
    for (int i = 0; i < 8; ++i){
      int c = t + 256 * i;
      int row = c >> 3, col = (c & 7) * 8;   // 256 rows x 8 chunks (128B/row)
      if (m0 + row < M)
        *(uint4*)(ob + (size_t)(m0 + row) * N + n0 + col) = *(const uint4*)&T[row * 72 + col];
    }
  } else {
    // fp32 out (proj, f_c2) + coalesced resid read. T: [128][68] floats (34.8KB), two halves.
    float* T = (float*)&SMEM[0];
    float* ob = (float*)outp + (size_t)bz * M * N;
    const float* rb = resid ? resid + (size_t)bz * M * N : nullptr;
    #pragma unroll
    for (int half = 0; half < 2; ++half){
      if ((w >> 1) == half){
        #pragma unroll
        for (int mt = 0; mt < 4; ++mt)
          #pragma unroll
          for (int nt = 0; nt < 4; ++nt)
            #pragma unroll
            for (int r = 0; r < 4; ++r){
              int ml = (w & 1) * 64 + mt * 16 + quad * 4 + r;   // 0..127 within half
              T[ml * 68 + nt * 16 + l16] = acc[mt][nt][r];
            }
      }
      __syncthreads();
      #pragma unroll
      for (int i = 0; i < 8; ++i){
        int c = t + 256 * i;
        int row = c >> 4, col = (c & 15) * 4;    // 128 rows x 16 chunks (256B/row)
        int m = m0 + half * 128 + row;
        if (m < M){
          size_t idx = (size_t)m * N + n0 + col;
          f32x4 v = *(const f32x4*)&T[row * 68 + col];
          float bv = bias[m];
          v[0] += bv; v[1] += bv; v[2] += bv; v[3] += bv;
          if (rb){
            v[0] += rb[idx]; v[1] += rb[idx + 1]; v[2] += rb[idx + 2]; v[3] += rb[idx + 3];
          }
          *(f32x4*)&ob[idx] = v;
        }
      }
      __syncthreads();
    }
  }
}

// ---------------- depthwise 3x3 (SAME) + bias + fused q/k sum-of-squares ----------------
__global__ __launch_bounds__(256) void dw3_k(const unsigned short* __restrict__ in,
                                             const float* __restrict__ w, const float* __restrict__ bias,
                                             unsigned short* __restrict__ out, int C,
                                             float* __restrict__ qn, float* __restrict__ kn){
  __shared__ unsigned short tile[66 * 128];
  __shared__ float red[4];
  int zc = blockIdx.y;
  int b = zc / C, c = zc - b * C;
  int r0 = blockIdx.x * 64;
  const unsigned short* im = in + ((size_t)(b * C + c)) * HW;
  unsigned short* om = out + ((size_t)(b * C + c)) * HW;
  int t = threadIdx.x;
  #pragma unroll
  for (int i = 0; i < 5; ++i){
    int idx = t + 256 * i;
    if (idx < 1056){
      int lr = idx >> 4, lc = (idx & 15) * 8;
      int gr = r0 - 1 + lr;
      uint4 v = {0u, 0u, 0u, 0u};
      if ((unsigned)gr < 128u) v = *(const uint4*)(im + gr * 128 + lc);
      *(uint4*)&tile[lr * 128 + lc] = v;
    }
  }
  __syncthreads();
  const float* wc = w + c * 9;
  float W[9];
  #pragma unroll
  for (int i = 0; i < 9; ++i) W[i] = wc[i];
  float bs = bias[c];
  float ssq = 0.f;
  #pragma unroll
  for (int i = 0; i < 4; ++i){
    int seg = t + 256 * i;
    int orow = seg >> 4, sc = (seg & 15) * 8;
    float acc[8];
    #pragma unroll
    for (int j = 0; j < 8; ++j) acc[j] = bs;
    #pragma unroll
    for (int rr = 0; rr < 3; ++rr){
      const unsigned short* rp = &tile[(orow + rr) * 128 + sc];
      float v[10];
      v[0] = (sc > 0) ? bf2f(rp[-1]) : 0.f;
      uint4 m = *(const uint4*)rp;
      const unsigned short* mu = (const unsigned short*)&m;
      #pragma unroll
      for (int j = 0; j < 8; ++j) v[j + 1] = bf2f(mu[j]);
      v[9] = (sc < 120) ? bf2f(rp[8]) : 0.f;
      float wa = W[rr * 3], wb = W[rr * 3 + 1], wd = W[rr * 3 + 2];
      #pragma unroll
      for (int j = 0; j < 8; ++j) acc[j] += wa * v[j] + wb * v[j + 1] + wd * v[j + 2];
    }
    unsigned short ob[8];
    #pragma unroll
    for (int j = 0; j < 8; ++j){
      ob[j] = f2bf(acc[j]);
      float q = bf2f(ob[j]);
      ssq += q * q;
    }
    *(uint4*)(om + (r0 + orow) * 128 + sc) = *(uint4*)ob;
  }
  if (c < 384){   // block-uniform branch
    #pragma unroll
    for (int off = 32; off; off >>= 1) ssq += __shfl_down(ssq, off);
    if ((t & 63) == 0) red[t >> 6] = ssq;
    __syncthreads();
    if (t == 0){
      float s = red[0] + red[1] + red[2] + red[3];
      float* dst = (c < 192) ? (qn + b * 192 + c) : (kn + b * 192 + c - 192);
      atomicAdd(dst, s);
    }
  }
}

// ---------------- GDFN: g = dw(h[0:510]) * dw(h[510:1020]), channel-major out ----------------
__global__ __launch_bounds__(256) void dwgate_k(const unsigned short* __restrict__ h,
                                                const float* __restrict__ w, const float* __restrict__ bias,
                                                unsigned short* __restrict__ g){
  __shared__ unsigned short tile[2 * 66 * 128];
  int zc = blockIdx.y;
  int b = zc / 510, j = zc - b * 510;
  int r0 = blockIdx.x * 64;
  const unsigned short* im1 = h + ((size_t)(b * 1020 + j)) * HW;
  const unsigned short* im2 = h + ((size_t)(b * 1020 + 510 + j)) * HW;
  int t = threadIdx.x;
  #pragma unroll
  for (int i = 0; i < 9; ++i){
    int idx = t + 256 * i;
    if (idx < 2112){
      int img = (idx >= 1056) ? 1 : 0;
      int li = idx - img * 1056;
      int lr = li >> 4, lc = (li & 15) * 8;
      int gr = r0 - 1 + lr;
      uint4 v = {0u, 0u, 0u, 0u};
      const unsigned short* im = img ? im2 : im1;
      if ((unsigned)gr < 128u) v = *(const uint4*)(im + gr * 128 + lc);
      *(uint4*)&tile[img * 8448 + lr * 128 + lc] = v;
    }
  }
  __syncthreads();
  float W1[9], W2[9];
  #pragma unroll
  for (int i = 0; i < 9; ++i){ W1[i] = w[j * 9 + i]; W2[i] = w[(510 + j) * 9 + i]; }
  float b1 = bias[j], b2 = bias[510 + j];
  unsigned short* gm = g + ((size_t)(b * 510 + j)) * HW;
  #pragma unroll
  for (int i = 0; i < 4; ++i){
    int seg = t + 256 * i;
    int orow = seg >> 4, sc = (seg & 15) * 8;
    float a1[8], a2[8];
    #pragma unroll
    for (int q = 0; q < 8; ++q){ a1[q] = b1; a2[q] = b2; }
    #pragma unroll
    for (int rr = 0; rr < 3; ++rr){
      #pragma unroll
      for (int img = 0; img < 2; ++img){
        const unsigned short* rp = &tile[img * 8448 + (orow + rr) * 128 + sc];
        float v[10];
        v[0] = (sc > 0) ? bf2f(rp[-1]) : 0.f;
        uint4 m = *(const uint4*)rp;
        const unsigned short* mu = (const unsigned short*)&m;
        #pragma unroll
        for (int q = 0; q < 8; ++q) v[q + 1] = bf2f(mu[q]);
        v[9] = (sc < 120) ? bf2f(rp[8]) : 0.f;
        const float* ww = img ? W2 : W1;
        float* aa = img ? a2 : a1;
        float wa = ww[rr * 3], wb = ww[rr * 3 + 1], wd = ww[rr * 3 + 2];
        #pragma unroll
        for (int q = 0; q < 8; ++q) aa[q] += wa * v[q] + wb * v[q + 1] + wd * v[q + 2];
      }
    }
    unsigned short ob[8];
    #pragma unroll
    for (int q = 0; q < 8; ++q) ob[q] = f2bf(a1[q] * a2[q]);
    *(uint4*)(gm + (r0 + orow) * 128 + sc) = *(uint4*)ob;
  }
}

// ---------------- transpose [C][HW] -> [HW][Kout] bf16, zero-pad channels >= C ----------------
__global__ __launch_bounds__(256) void tr_k(const unsigned short* __restrict__ in,
                                            unsigned short* __restrict__ out, int C, int Kout){
  __shared__ unsigned short tile[64 * 72];
  int b = blockIdx.z;
  int p0 = blockIdx.x * 64, c0 = blockIdx.y * 64;
  int t = threadIdx.x;
  #pragma unroll
  for (int i = 0; i < 2; ++i){
    int id = t + 256 * i;               // 512 chunks: 64ch x 8
    int ch = id >> 3, pc = (id & 7) * 8;
    uint4 v = {0u, 0u, 0u, 0u};
    if (c0 + ch < C) v = *(const uint4*)(in + ((size_t)(b * C + c0 + ch)) * HW + p0 + pc);
    const unsigned short* u = (const unsigned short*)&v;
    #pragma unroll
    for (int j = 0; j < 8; ++j) tile[(pc + j) * 72 + ch] = u[j];
  }
  __syncthreads();
  #pragma unroll
  for (int i = 0; i < 2; ++i){
    int id = t + 256 * i;               // 512 chunks: 64px x 8
    int px = id >> 3, cc = (id & 7) * 8;
    *(uint4*)(out + ((size_t)b * HW + p0 + px) * Kout + c0 + cc) = *(const uint4*)&tile[px * 72 + cc];
  }
}

// ---------------- QK^T via MFMA, K-split partials. grid (32 ksplit, 32 bh), 1 wave ----------------
__global__ __launch_bounds__(64) void qk_k(const unsigned short* __restrict__ qkv_dw, float* __restrict__ part){
  int bh = blockIdx.y; int b = bh >> 3, h = bh & 7;
  int ks = blockIdx.x;
  int lane = threadIdx.x;
  int l16 = lane & 15, quad = lane >> 4;
  const unsigned short* qb = qkv_dw + ((size_t)b * 576 + h * 24) * HW;
  const unsigned short* kb = qkv_dw + ((size_t)b * 576 + 192 + h * 24) * HW;
  f32x4 z = {0.f, 0.f, 0.f, 0.f};
  f32x4 a00 = z, a01 = z, a10 = z, a11 = z;
  for (int st = 0; st < 16; ++st){
    int k0 = ks * 512 + st * 32 + quad * 8;
    short8 qa0 = *(const short8*)(qb + (size_t)l16 * HW + k0);
    short8 qa1 = *(const short8*)(qb + (size_t)(l16 + 16) * HW + k0);
    short8 kb0 = *(const short8*)(kb + (size_t)l16 * HW + k0);
    short8 kb1 = *(const short8*)(kb + (size_t)(l16 + 16) * HW + k0);
    a00 = __builtin_amdgcn_mfma_f32_16x16x32_bf16(qa0, kb0, a00, 0, 0, 0);
    a01 = __builtin_amdgcn_mfma_f32_16x16x32_bf16(qa0, kb1, a01, 0, 0, 0);
    a10 = __builtin_amdgcn_mfma_f32_16x16x32_bf16(qa1, kb0, a10, 0, 0, 0);
    a11 = __builtin_amdgcn_mfma_f32_16x16x32_bf16(qa1, kb1, a11, 0, 0, 0);
  }
  float* pp = part + ((size_t)bh * 32 + ks) * 576;
  #pragma unroll
  for (int r = 0; r < 4; ++r){
    int c0 = quad * 4 + r, c1 = 16 + quad * 4 + r;
    int d0 = l16, d1 = 16 + l16;
    if (c0 < 24 && d0 < 24) pp[c0 * 24 + d0] = a00[r];
    if (c0 < 24 && d1 < 24) pp[c0 * 24 + d1] = a01[r];
    if (c1 < 24 && d0 < 24) pp[c1 * 24 + d0] = a10[r];
    if (c1 < 24 && d1 < 24) pp[c1 * 24 + d1] = a11[r];
  }
}

// ---------------- reduce partials, scale by temp/(|q||k|), softmax over d ----------------
__global__ void softmax_k(const float* __restrict__ part, const float* __restrict__ qn,
                          const float* __restrict__ kn, const float* __restrict__ temp,
                          float* __restrict__ attn){
  int bh = blockIdx.x; int b = bh >> 3, h = bh & 7;
  int c = threadIdx.x;
  if (c >= 24) return;
  float tmp = temp[h];
  float qv = fmaxf(sqrtf(qn[b * 192 + h * 24 + c]), 1e-12f);
  float row[24];
  #pragma unroll
  for (int d = 0; d < 24; ++d){
    float s = 0.f;
    for (int sp = 0; sp < 32; ++sp) s += part[((size_t)bh * 32 + sp) * 576 + c * 24 + d];
    float kv = fmaxf(sqrtf(kn[b * 192 + h * 24 + d]), 1e-12f);
    row[d] = s * tmp / (qv * kv);
  }
  float mx = row[0];
  #pragma unroll
  for (int d = 1; d < 24; ++d) mx = fmaxf(mx, row[d]);
  float sum = 0.f;
  #pragma unroll
  for (int d = 0; d < 24; ++d){ row[d] = expf(row[d] - mx); sum += row[d]; }
  float inv = 1.f / sum;
  #pragma unroll
  for (int d = 0; d < 24; ++d) attn[(size_t)bh * 576 + c * 24 + d] = row[d] * inv;
}

// ---------------- out[p][c] = sum_d attn[c][d] * v[d][p]  (PIXEL-MAJOR out) ----------------
__global__ __launch_bounds__(256) void av_k(const float* __restrict__ attn,
                                            const unsigned short* __restrict__ qkv_dw,
                                            unsigned short* __restrict__ o){
  int bh = blockIdx.y; int b = bh >> 3, h = bh & 7;
  __shared__ float As[576];
  int t = threadIdx.x;
  for (int i = t; i < 576; i += 256) As[i] = attn[(size_t)bh * 576 + i];
  __syncthreads();
  int p = blockIdx.x * 256 + t;
  const unsigned short* vb = qkv_dw + ((size_t)b * 576 + 384 + h * 24) * HW + p;
  float acc[24];
  #pragma unroll
  for (int c = 0; c < 24; ++c) acc[c] = 0.f;
  #pragma unroll
  for (int d = 0; d < 24; ++d){
    float vv = bf2f(vb[(size_t)d * HW]);
    #pragma unroll
    for (int c = 0; c < 24; ++c) acc[c] += As[c * 24 + d] * vv;
  }
  unsigned short ob[24];
  #pragma unroll
  for (int c = 0; c < 24; ++c) ob[c] = f2bf(acc[c]);
  unsigned short* op = o + ((size_t)b * HW + p) * 192 + h * 24;
  #pragma unroll
  for (int i = 0; i < 3; ++i) *(uint4*)(op + i * 8) = *(const uint4*)(ob + i * 8);
}

extern "C" void kernel_launch(void* const* d_in, const int* in_sizes, int n_in,
                              void* d_out, int out_size, void* d_ws, size_t ws_size,
                              hipStream_t stream){
  (void)in_sizes; (void)n_in; (void)out_size; (void)ws_size;
  const float* x        = (const float*)d_in[0];
  const float* t_emb    = (const float*)d_in[1];
  const float* n1_w     = (const float*)d_in[2];
  const float* n1_b     = (const float*)d_in[3];
  const float* temp     = (const float*)d_in[4];
  const float* a_qkv_w  = (const float*)d_in[5];
  const float* a_qkv_b  = (const float*)d_in[6];
  const float* a_dw_w   = (const float*)d_in[7];
  const float* a_dw_b   = (const float*)d_in[8];
  const float* a_proj_w = (const float*)d_in[9];
  const float* a_proj_b = (const float*)d_in[10];
  const float* a_t_w    = (const float*)d_in[11];
  const float* a_t_b    = (const float*)d_in[12];
  const float* n2_w     = (const float*)d_in[13];
  const float* n2_b     = (const float*)d_in[14];
  const float* f_c1_w   = (const float*)d_in[15];
  const float* f_c1_b   = (const float*)d_in[16];
  const float* f_dw_w   = (const float*)d_in[17];
  const float* f_dw_b   = (const float*)d_in[18];
  const float* f_c2_w   = (const float*)d_in[19];
  const float* f_c2_b   = (const float*)d_in[20];
  const float* f_t_w    = (const float*)d_in[21];
  const float* f_t_b    = (const float*)d_in[22];
  float* out = (float*)d_out;
  char* ws = (char*)d_ws;

  // workspace layout (~229 MB, phase-overlapped)
  unsigned short* y_buf = (unsigned short*)(ws + 0);          // [b][p][192] 25.2MB
  unsigned short* qkv   = (unsigned short*)(ws + 25165824);   // [b][576][HW] 75.5MB (stage A)
  unsigned short* hbuf  = (unsigned short*)(ws + 25165824);   // [b][1020][HW] 133.7MB (stage B)
  unsigned short* gbufT = (unsigned short*)(ws + 25165824);   // [b][p][512] 67.1MB (after dwgate)
  unsigned short* qkvd  = (unsigned short*)(ws + 100663296);  // [b][576][HW] 75.5MB
  unsigned short* obuf  = (unsigned short*)(ws + 176160768);  // [b][p][192] 25.2MB
  unsigned short* gbuf  = (unsigned short*)(ws + 158859264);  // [b][510][HW] 66.8MB
  const size_t S = 225705984;
  float* mod_a = (float*)(ws + S);
  float* mod_f = (float*)(ws + S + 8192);
  float* qn    = (float*)(ws + S + 16384);
  float* kn    = (float*)(ws + S + 20480);
  float* part  = (float*)(ws + S + 24576);        // 2359296
  float* attn  = (float*)(ws + S + 2383872);      // 73728
  unsigned short* Wq  = (unsigned short*)(ws + S + 2457600);  // 576x192
  unsigned short* Wp  = (unsigned short*)(ws + S + 2678784);  // 192x192
  unsigned short* W1  = (unsigned short*)(ws + S + 2752512);  // 1020x192
  unsigned short* W2p = (unsigned short*)(ws + S + 3144192);  // 192x512 (padded)

  castw_k<<<dim3((110592 + 255) / 256), 256, 0, stream>>>(a_qkv_w, Wq, 110592);
  castw_k<<<dim3((36864 + 255) / 256), 256, 0, stream>>>(a_proj_w, Wp, 36864);
  castw_k<<<dim3((195840 + 255) / 256), 256, 0, stream>>>(f_c1_w, W1, 195840);
  castw_pad_k<<<dim3((98304 + 255) / 256), 256, 0, stream>>>(f_c2_w, W2p, 192, 510, 512);
  modk<<<dim3(3, 4, 2), 128, 0, stream>>>(t_emb, a_t_w, a_t_b, f_t_w, f_t_b, mod_a, mod_f);
  (void)hipMemsetAsync(qn, 0, 2 * 768 * sizeof(float), stream);  // qn+kn contiguous

  // ---- MDTA branch ----
  lnmod_k<<<dim3(64, 4), 256, 0, stream>>>(x, n1_w, n1_b, mod_a, y_buf);
  gemm_tn2<<<dim3(3, 256, 4), 256, 0, stream>>>(Wq, y_buf, a_qkv_b, nullptr, qkv, 576, 192, 0);
  dw3_k<<<dim3(2, 2304), 256, 0, stream>>>(qkv, a_dw_w, a_dw_b, qkvd, 576, qn, kn);
  qk_k<<<dim3(32, 32), 64, 0, stream>>>(qkvd, part);
  softmax_k<<<32, 64, 0, stream>>>(part, qn, kn, temp, attn);
  av_k<<<dim3(64, 32), 256, 0, stream>>>(attn, qkvd, obuf);
  gemm_tn2<<<dim3(1, 256, 4), 256, 0, stream>>>(Wp, obuf, a_proj_b, x, out, 192, 192, 1); // out = x1

  // ---- GDFN branch ----
  lnmod_k<<<dim3(64, 4), 256, 0, stream>>>(out, n2_w, n2_b, mod_f, y_buf);
  gemm_tn2<<<dim3(4, 256, 4), 256, 0, stream>>>(W1, y_buf, f_c1_b, nullptr, hbuf, 1020, 192, 0);
  dwgate_k<<<dim3(2, 2040), 256, 0, stream>>>(hbuf, f_dw_w, f_dw_b, gbuf);
  tr_k<<<dim3(256, 8, 4), 256, 0, stream>>>(gbuf, gbufT, 510, 512);
  gemm_tn2<<<dim3(1, 256, 4), 256, 0, stream>>>(W2p, gbufT, f_c2_b, out, out, 192, 512, 1);
}

// Round 13
// 739.640 us; speedup vs baseline: 1.0551x; 1.0422x over previous
//
#include <hip/hip_runtime.h>
#include <math.h>

#define HW 16384

using short8 = __attribute__((ext_vector_type(8))) short;
using f32x4  = __attribute__((ext_vector_type(4))) float;

__device__ __forceinline__ float bf2f(unsigned short u){
  union { unsigned int i; float f; } x; x.i = ((unsigned int)u) << 16; return x.f;
}
__device__ __forceinline__ unsigned short f2bf(float f){
  union { float f; unsigned int i; } x; x.f = f;
  return (unsigned short)((x.i + 0x7FFFu + ((x.i >> 16) & 1u)) >> 16);
}

// ---------------- weight fp32 -> bf16 ----------------
__global__ void castw_k(const float* __restrict__ in, unsigned short* __restrict__ out, int n){
  int i = blockIdx.x * 256 + threadIdx.x;
  if (i < n) out[i] = f2bf(in[i]);
}
// cast + pad K: in [M][Kin] -> out [M][Kout], zeros beyond Kin
__global__ void castw_pad_k(const float* __restrict__ in, unsigned short* __restrict__ out,
                            int M, int Kin, int Kout){
  int i = blockIdx.x * 256 + threadIdx.x;
  if (i < M * Kout){
    int m = i / Kout, k = i - m * Kout;
    out[i] = (k < Kin) ? f2bf(in[m * Kin + k]) : (unsigned short)0;
  }
}

// ---------------- time modulation: silu(t_emb) @ W^T + b ----------------
__global__ void modk(const float* __restrict__ t_emb,
                     const float* __restrict__ aw, const float* __restrict__ ab,
                     const float* __restrict__ fw, const float* __restrict__ fb,
                     float* __restrict__ mod_a, float* __restrict__ mod_f){
  int o = blockIdx.x * 128 + threadIdx.x;   // 0..383
  int b = blockIdx.y;
  const float* w  = blockIdx.z ? fw : aw;
  const float* bi = blockIdx.z ? fb : ab;
  float* outp     = blockIdx.z ? mod_f : mod_a;
  const float* te = t_emb + b * 256;
  float acc = bi[o];
  for (int k = 0; k < 256; ++k){
    float u = te[k];
    float s = u / (1.f + expf(-u));
    acc += s * w[o * 256 + k];
  }
  outp[b * 384 + o] = acc;
}

// ---------------- channel LayerNorm (ddof=1, std+eps) + modulate -> bf16 PIXEL-MAJOR --------------
// One thread per pixel: no LDS, no barrier; full 384B row per thread.
__global__ __launch_bounds__(256) void lnmod_k(const float* __restrict__ x,
                                               const float* __restrict__ nw, const float* __restrict__ nb,
                                               const float* __restrict__ mod, unsigned short* __restrict__ y){
  int b = blockIdx.y;
  int p = blockIdx.x * 256 + threadIdx.x;
  const float* xb = x + (size_t)b * 192 * HW + p;
  float s = 0.f, s2 = 0.f;
  #pragma unroll 8
  for (int c = 0; c < 192; ++c){
    float v = xb[(size_t)c * HW]; s += v; s2 += v * v;
  }
  float mean = s * (1.f / 192.f);
  float var  = (s2 - s * mean) * (1.f / 191.f);
  float rinv = 1.f / (sqrtf(fmaxf(var, 0.f)) + 1e-6f);
  const float* mo = mod + b * 384;
  unsigned short* yb = y + ((size_t)b * HW + p) * 192;
  #pragma unroll
  for (int c8 = 0; c8 < 24; ++c8){
    unsigned short ob[8];
    #pragma unroll
    for (int j = 0; j < 8; ++j){
      int c = c8 * 8 + j;
      float v = xb[(size_t)c * HW];
      float ln = nw[c] * ((v - mean) * rinv) + nb[c];
      ob[j] = f2bf(ln * (1.f + mo[c]) + mo[192 + c]);
    }
    *(uint4*)(yb + c8 * 8) = *(const uint4*)ob;
  }
}

// ---------------- bf16 MFMA GEMM (round-9 structure): dbuf + XCD swizzle + coalesced epilogue -----
// out[b][m][n] = W[m][k] @ Act[b][n][k] + bias (+resid). K mult of 32.
// BM=64, BN=256, BK=32, 4 waves. 1-D grid, panel-major logical order + XCD swizzle.
// CMAJ=0: act rows k-contiguous [N][K]. CMAJ=C>0: act channel-major [C][HW]; B-tile staged via
// coalesced 512B channel-row reads + scalar LDS transpose into the same Bs[px][k] layout
// (channels >= C clamp to C-1; weight columns there are zero). Kills the tr_k dispatch.
template<int CMAJ>
__global__ __launch_bounds__(256, 2) void gemm_tn2(const unsigned short* __restrict__ A,
                                                   const unsigned short* __restrict__ Bact,
                                                   const float* __restrict__ bias,
                                                   const float* resid, void* outp,
                                                   int M, int K, int nMb, int ofp32){
  const int N = HW;
  __shared__ unsigned short SMEM[20480];     // As dbuf at 0/2048 shorts x2; Bs dbuf at 4096 + cur*8192
  const int G = gridDim.x;
  const int bid = blockIdx.x;
  const int lb = (bid & 7) * (G >> 3) + (bid >> 3);
  const int mb = lb % nMb;
  const int rest = lb / nMb;
  const int n0 = (rest & 63) * 256;
  const int bz = rest >> 6;
  const int m0 = mb * 64;
  const int t = threadIdx.x;
  const int w = t >> 6, lane = t & 63;
  const int l16 = lane & 15, quad = lane >> 4;

  // A staging geometry: phys slot = logical slot ^ ((row ^ row>>2) & 3)
  const int arow = t >> 2, akc = t & 3;
  int gm = m0 + arow; if (gm > M - 1) gm = M - 1;     // clamp; masked in epilogue
  const unsigned short* agp = A + (size_t)gm * K + akc * 8;
  const int aoff = arow * 32 + ((akc ^ ((arow ^ (arow >> 2)) & 3)) * 8);

  // B staging geometry
  const unsigned short* Bp;
  const int brow = t >> 2, bkc = t & 3;
  int bslot = 0;
  if (CMAJ == 0){
    Bp = Bact + (size_t)bz * N * K;
    bslot = (bkc ^ ((brow ^ (brow >> 2)) & 3)) * 8;   // row+64i keeps bits0-3 -> same
  } else {
    Bp = Bact + (size_t)bz * CMAJ * HW;
  }

  f32x4 acc[4][4];
  #pragma unroll
  for (int i = 0; i < 4; ++i)
    #pragma unroll
    for (int j = 0; j < 4; ++j) acc[i][j] = (f32x4){0.f, 0.f, 0.f, 0.f};

  const int kTiles = K >> 5;
  {  // prologue: stage tile 0 into buf 0
    *(uint4*)&SMEM[aoff] = *(const uint4*)agp;
    if (CMAJ == 0){
      const unsigned short* bgp = Bp + (size_t)(n0 + brow) * K + bkc * 8;
      #pragma unroll
      for (int i = 0; i < 4; ++i)
        *(uint4*)&SMEM[4096 + (brow + 64 * i) * 32 + bslot] = *(const uint4*)(bgp + (size_t)(64 * i) * K);
    } else {
      #pragma unroll
      for (int i = 0; i < 4; ++i){
        int id = t + 256 * i;
        int chl = id >> 5, po = (id & 31) * 8;
        int cg = chl; if (cg > CMAJ - 1) cg = CMAJ - 1;
        uint4 v = *(const uint4*)(Bp + (size_t)cg * HW + n0 + po);
        const unsigned short* u = (const unsigned short*)&v;
        #pragma unroll
        for (int j = 0; j < 8; ++j){
          int px = po + j;
          int phys = (chl >> 3) ^ ((px ^ (px >> 2)) & 3);
          SMEM[4096 + px * 32 + phys * 8 + (chl & 7)] = u[j];
        }
      }
    }
  }
  __syncthreads();

  const int fs = (quad ^ ((l16 ^ (l16 >> 2)) & 3)) * 8;   // fragment phys slot (2-way banks)
  for (int kt = 0; kt < kTiles; ++kt){
    const int cur = kt & 1;
    const bool more = (kt + 1 < kTiles);
    uint4 va; uint4 vb[4];
    if (more){
      const int k0 = (kt + 1) * 32;
      va = *(const uint4*)(agp + k0);
      if (CMAJ == 0){
        const unsigned short* bgp = Bp + (size_t)(n0 + brow) * K + bkc * 8;
        #pragma unroll
        for (int i = 0; i < 4; ++i)
          vb[i] = *(const uint4*)(bgp + (size_t)(64 * i) * K + k0);
      } else {
        #pragma unroll
        for (int i = 0; i < 4; ++i){
          int id = t + 256 * i;
          int chl = id >> 5;
          int cg = k0 + chl; if (cg > CMAJ - 1) cg = CMAJ - 1;
          vb[i] = *(const uint4*)(Bp + (size_t)cg * HW + n0 + (id & 31) * 8);
        }
      }
    }
    const int abase = cur * 2048;
    const int bbase = 4096 + cur * 8192;
    short8 af[4], bfr[4];
    #pragma unroll
    for (int mt = 0; mt < 4; ++mt)
      af[mt] = *(const short8*)&SMEM[abase + (mt * 16 + l16) * 32 + fs];
    #pragma unroll
    for (int nt = 0; nt < 4; ++nt)
      bfr[nt] = *(const short8*)&SMEM[bbase + (w * 64 + nt * 16 + l16) * 32 + fs];
    #pragma unroll
    for (int nt = 0; nt < 4; ++nt)
      #pragma unroll
      for (int mt = 0; mt < 4; ++mt)
        acc[mt][nt] = __builtin_amdgcn_mfma_f32_16x16x32_bf16(af[mt], bfr[nt], acc[mt][nt], 0, 0, 0);
    if (more){
      const int nabase = (cur ^ 1) * 2048;
      const int nbbase = 4096 + (cur ^ 1) * 8192;
      *(uint4*)&SMEM[nabase + aoff] = va;
      if (CMAJ == 0){
        #pragma unroll
        for (int i = 0; i < 4; ++i)
          *(uint4*)&SMEM[nbbase + (brow + 64 * i) * 32 + bslot] = vb[i];
      } else {
        #pragma unroll
        for (int i = 0; i < 4; ++i){
          int id = t + 256 * i;
          int chl = id >> 5, po = (id & 31) * 8;
          const unsigned short* u = (const unsigned short*)&vb[i];
          #pragma unroll
          for (int j = 0; j < 8; ++j){
            int px = po + j;
            int phys = (chl >> 3) ^ ((px ^ (px >> 2)) & 3);
            SMEM[nbbase + px * 32 + phys * 8 + (chl & 7)] = u[j];
          }
        }
      }
    }
    __syncthreads();
  }

  // ---- epilogue: LDS transpose -> coalesced global I/O ----
  if (!ofp32){
    // bf16 out (qkv, f_c1). T: [64][264] shorts (16896 <= 20480)
    unsigned short* T = SMEM;
    #pragma unroll
    for (int mt = 0; mt < 4; ++mt)
      #pragma unroll
      for (int nt = 0; nt < 4; ++nt)
        #pragma unroll
        for (int r = 0; r < 4; ++r){
          int ml = mt * 16 + quad * 4 + r;
          int bm = m0 + ml; if (bm > M - 1) bm = M - 1;
          T[ml * 264 + w * 64 + nt * 16 + l16] = f2bf(acc[mt][nt][r] + bias[bm]);
        }
    __syncthreads();
    unsigned short* ob = (unsigned short*)outp + (size_t)bz * M * N;
    #pragma unroll
    for (int i = 0; i < 8; ++i){
      int c = t + 256 * i;
      int row = c >> 5, col = (c & 31) * 8;   // 32 chunks x 64 rows
      if (m0 + row < M)
        *(uint4*)(ob + (size_t)(m0 + row) * N + n0 + col) = *(const uint4*)&T[row * 264 + col];
    }
  } else {
    // fp32 out (proj, f_c2) + coalesced resid read. T: [32][260] floats (33.3KB), two halves.
    float* T = (float*)&SMEM[0];
    float* ob = (float*)outp + (size_t)bz * M * N;
    const float* rb = resid ? resid + (size_t)bz * M * N : nullptr;
    #pragma unroll
    for (int half = 0; half < 2; ++half){
      #pragma unroll
      for (int mt = 0; mt < 2; ++mt)
        #pragma unroll
        for (int nt = 0; nt < 4; ++nt)
          #pragma unroll
          for (int r = 0; r < 4; ++r){
            int ml = mt * 16 + quad * 4 + r;            // 0..31 within half
            T[ml * 260 + w * 64 + nt * 16 + l16] = acc[half * 2 + mt][nt][r];
          }
      __syncthreads();
      #pragma unroll
      for (int i = 0; i < 8; ++i){
        int c = t + 256 * i;
        int row = c >> 6, col = (c & 63) * 4;           // 64 chunks x 32 rows
        int m = m0 + half * 32 + row;
        if (m < M){
          size_t idx = (size_t)m * N + n0 + col;
          f32x4 v = *(const f32x4*)&T[row * 260 + col];
          float bv = bias[m];
          v[0] += bv; v[1] += bv; v[2] += bv; v[3] += bv;
          if (rb){
            v[0] += rb[idx]; v[1] += rb[idx + 1]; v[2] += rb[idx + 2]; v[3] += rb[idx + 3];
          }
          *(f32x4*)&ob[idx] = v;
        }
      }
      __syncthreads();
    }
  }
}

// ---------------- depthwise 3x3 (SAME) + bias + fused q/k sum-of-squares ----------------
__global__ __launch_bounds__(256) void dw3_k(const unsigned short* __restrict__ in,
                                             const float* __restrict__ w, const float* __restrict__ bias,
                                             unsigned short* __restrict__ out, int C,
                                             float* __restrict__ qn, float* __restrict__ kn){
  __shared__ unsigned short tile[66 * 128];
  __shared__ float red[4];
  int zc = blockIdx.y;
  int b = zc / C, c = zc - b * C;
  int r0 = blockIdx.x * 64;
  const unsigned short* im = in + ((size_t)(b * C + c)) * HW;
  unsigned short* om = out + ((size_t)(b * C + c)) * HW;
  int t = threadIdx.x;
  #pragma unroll
  for (int i = 0; i < 5; ++i){
    int idx = t + 256 * i;
    if (idx < 1056){
      int lr = idx >> 4, lc = (idx & 15) * 8;
      int gr = r0 - 1 + lr;
      uint4 v = {0u, 0u, 0u, 0u};
      if ((unsigned)gr < 128u) v = *(const uint4*)(im + gr * 128 + lc);
      *(uint4*)&tile[lr * 128 + lc] = v;
    }
  }
  __syncthreads();
  const float* wc = w + c * 9;
  float W[9];
  #pragma unroll
  for (int i = 0; i < 9; ++i) W[i] = wc[i];
  float bs = bias[c];
  float ssq = 0.f;
  #pragma unroll
  for (int i = 0; i < 4; ++i){
    int seg = t + 256 * i;
    int orow = seg >> 4, sc = (seg & 15) * 8;
    float acc[8];
    #pragma unroll
    for (int j = 0; j < 8; ++j) acc[j] = bs;
    #pragma unroll
    for (int rr = 0; rr < 3; ++rr){
      const unsigned short* rp = &tile[(orow + rr) * 128 + sc];
      float v[10];
      v[0] = (sc > 0) ? bf2f(rp[-1]) : 0.f;
      uint4 m = *(const uint4*)rp;
      const unsigned short* mu = (const unsigned short*)&m;
      #pragma unroll
      for (int j = 0; j < 8; ++j) v[j + 1] = bf2f(mu[j]);
      v[9] = (sc < 120) ? bf2f(rp[8]) : 0.f;
      float wa = W[rr * 3], wb = W[rr * 3 + 1], wd = W[rr * 3 + 2];
      #pragma unroll
      for (int j = 0; j < 8; ++j) acc[j] += wa * v[j] + wb * v[j + 1] + wd * v[j + 2];
    }
    unsigned short ob[8];
    #pragma unroll
    for (int j = 0; j < 8; ++j){
      ob[j] = f2bf(acc[j]);
      float q = bf2f(ob[j]);
      ssq += q * q;
    }
    *(uint4*)(om + (r0 + orow) * 128 + sc) = *(uint4*)ob;
  }
  if (c < 384){   // block-uniform branch
    #pragma unroll
    for (int off = 32; off; off >>= 1) ssq += __shfl_down(ssq, off);
    if ((t & 63) == 0) red[t >> 6] = ssq;
    __syncthreads();
    if (t == 0){
      float s = red[0] + red[1] + red[2] + red[3];
      float* dst = (c < 192) ? (qn + b * 192 + c) : (kn + b * 192 + c - 192);
      atomicAdd(dst, s);
    }
  }
}

// ---------------- GDFN: g = dw(h[0:510]) * dw(h[510:1020]), channel-major out ----------------
__global__ __launch_bounds__(256) void dwgate_k(const unsigned short* __restrict__ h,
                                                const float* __restrict__ w, const float* __restrict__ bias,
                                                unsigned short* __restrict__ g){
  __shared__ unsigned short tile[2 * 66 * 128];
  int zc = blockIdx.y;
  int b = zc / 510, j = zc - b * 510;
  int r0 = blockIdx.x * 64;
  const unsigned short* im1 = h + ((size_t)(b * 1020 + j)) * HW;
  const unsigned short* im2 = h + ((size_t)(b * 1020 + 510 + j)) * HW;
  int t = threadIdx.x;
  #pragma unroll
  for (int i = 0; i < 9; ++i){
    int idx = t + 256 * i;
    if (idx < 2112){
      int img = (idx >= 1056) ? 1 : 0;
      int li = idx - img * 1056;
      int lr = li >> 4, lc = (li & 15) * 8;
      int gr = r0 - 1 + lr;
      uint4 v = {0u, 0u, 0u, 0u};
      const unsigned short* im = img ? im2 : im1;
      if ((unsigned)gr < 128u) v = *(const uint4*)(im + gr * 128 + lc);
      *(uint4*)&tile[img * 8448 + lr * 128 + lc] = v;
    }
  }
  __syncthreads();
  float W1[9], W2[9];
  #pragma unroll
  for (int i = 0; i < 9; ++i){ W1[i] = w[j * 9 + i]; W2[i] = w[(510 + j) * 9 + i]; }
  float b1 = bias[j], b2 = bias[510 + j];
  unsigned short* gm = g + ((size_t)(b * 510 + j)) * HW;
  #pragma unroll
  for (int i = 0; i < 4; ++i){
    int seg = t + 256 * i;
    int orow = seg >> 4, sc = (seg & 15) * 8;
    float a1[8], a2[8];
    #pragma unroll
    for (int q = 0; q < 8; ++q){ a1[q] = b1; a2[q] = b2; }
    #pragma unroll
    for (int rr = 0; rr < 3; ++rr){
      #pragma unroll
      for (int img = 0; img < 2; ++img){
        const unsigned short* rp = &tile[img * 8448 + (orow + rr) * 128 + sc];
        float v[10];
        v[0] = (sc > 0) ? bf2f(rp[-1]) : 0.f;
        uint4 m = *(const uint4*)rp;
        const unsigned short* mu = (const unsigned short*)&m;
        #pragma unroll
        for (int q = 0; q < 8; ++q) v[q + 1] = bf2f(mu[q]);
        v[9] = (sc < 120) ? bf2f(rp[8]) : 0.f;
        const float* ww = img ? W2 : W1;
        float* aa = img ? a2 : a1;
        float wa = ww[rr * 3], wb = ww[rr * 3 + 1], wd = ww[rr * 3 + 2];
        #pragma unroll
        for (int q = 0; q < 8; ++q) aa[q] += wa * v[q] + wb * v[q + 1] + wd * v[q + 2];
      }
    }
    unsigned short ob[8];
    #pragma unroll
    for (int q = 0; q < 8; ++q) ob[q] = f2bf(a1[q] * a2[q]);
    *(uint4*)(gm + (r0 + orow) * 128 + sc) = *(uint4*)ob;
  }
}

// ---------------- QK^T via MFMA, K-split partials. grid (32 ksplit, 32 bh), 1 wave ----------------
__global__ __launch_bounds__(64) void qk_k(const unsigned short* __restrict__ qkv_dw, float* __restrict__ part){
  int bh = blockIdx.y; int b = bh >> 3, h = bh & 7;
  int ks = blockIdx.x;
  int lane = threadIdx.x;
  int l16 = lane & 15, quad = lane >> 4;
  const unsigned short* qb = qkv_dw + ((size_t)b * 576 + h * 24) * HW;
  const unsigned short* kb = qkv_dw + ((size_t)b * 576 + 192 + h * 24) * HW;
  f32x4 z = {0.f, 0.f, 0.f, 0.f};
  f32x4 a00 = z, a01 = z, a10 = z, a11 = z;
  for (int st = 0; st < 16; ++st){
    int k0 = ks * 512 + st * 32 + quad * 8;
    short8 qa0 = *(const short8*)(qb + (size_t)l16 * HW + k0);
    short8 qa1 = *(const short8*)(qb + (size_t)(l16 + 16) * HW + k0);
    short8 kb0 = *(const short8*)(kb + (size_t)l16 * HW + k0);
    short8 kb1 = *(const short8*)(kb + (size_t)(l16 + 16) * HW + k0);
    a00 = __builtin_amdgcn_mfma_f32_16x16x32_bf16(qa0, kb0, a00, 0, 0, 0);
    a01 = __builtin_amdgcn_mfma_f32_16x16x32_bf16(qa0, kb1, a01, 0, 0, 0);
    a10 = __builtin_amdgcn_mfma_f32_16x16x32_bf16(qa1, kb0, a10, 0, 0, 0);
    a11 = __builtin_amdgcn_mfma_f32_16x16x32_bf16(qa1, kb1, a11, 0, 0, 0);
  }
  float* pp = part + ((size_t)bh * 32 + ks) * 576;
  #pragma unroll
  for (int r = 0; r < 4; ++r){
    int c0 = quad * 4 + r, c1 = 16 + quad * 4 + r;
    int d0 = l16, d1 = 16 + l16;
    if (c0 < 24 && d0 < 24) pp[c0 * 24 + d0] = a00[r];
    if (c0 < 24 && d1 < 24) pp[c0 * 24 + d1] = a01[r];
    if (c1 < 24 && d0 < 24) pp[c1 * 24 + d0] = a10[r];
    if (c1 < 24 && d1 < 24) pp[c1 * 24 + d1] = a11[r];
  }
}

// ---------------- reduce partials, scale by temp/(|q||k|), softmax over d ----------------
__global__ void softmax_k(const float* __restrict__ part, const float* __restrict__ qn,
                          const float* __restrict__ kn, const float* __restrict__ temp,
                          float* __restrict__ attn){
  int bh = blockIdx.x; int b = bh >> 3, h = bh & 7;
  int c = threadIdx.x;
  if (c >= 24) return;
  float tmp = temp[h];
  float qv = fmaxf(sqrtf(qn[b * 192 + h * 24 + c]), 1e-12f);
  float row[24];
  #pragma unroll
  for (int d = 0; d < 24; ++d){
    float s = 0.f;
    for (int sp = 0; sp < 32; ++sp) s += part[((size_t)bh * 32 + sp) * 576 + c * 24 + d];
    float kv = fmaxf(sqrtf(kn[b * 192 + h * 24 + d]), 1e-12f);
    row[d] = s * tmp / (qv * kv);
  }
  float mx = row[0];
  #pragma unroll
  for (int d = 1; d < 24; ++d) mx = fmaxf(mx, row[d]);
  float sum = 0.f;
  #pragma unroll
  for (int d = 0; d < 24; ++d){ row[d] = expf(row[d] - mx); sum += row[d]; }
  float inv = 1.f / sum;
  #pragma unroll
  for (int d = 0; d < 24; ++d) attn[(size_t)bh * 576 + c * 24 + d] = row[d] * inv;
}

// ---------------- out[p][c] = sum_d attn[c][d] * v[d][p]  (PIXEL-MAJOR out) ----------------
__global__ __launch_bounds__(256) void av_k(const float* __restrict__ attn,
                                            const unsigned short* __restrict__ qkv_dw,
                                            unsigned short* __restrict__ o){
  int bh = blockIdx.y; int b = bh >> 3, h = bh & 7;
  __shared__ float As[576];
  int t = threadIdx.x;
  for (int i = t; i < 576; i += 256) As[i] = attn[(size_t)bh * 576 + i];
  __syncthreads();
  int p = blockIdx.x * 256 + t;
  const unsigned short* vb = qkv_dw + ((size_t)b * 576 + 384 + h * 24) * HW + p;
  float acc[24];
  #pragma unroll
  for (int c = 0; c < 24; ++c) acc[c] = 0.f;
  #pragma unroll
  for (int d = 0; d < 24; ++d){
    float vv = bf2f(vb[(size_t)d * HW]);
    #pragma unroll
    for (int c = 0; c < 24; ++c) acc[c] += As[c * 24 + d] * vv;
  }
  unsigned short ob[24];
  #pragma unroll
  for (int c = 0; c < 24; ++c) ob[c] = f2bf(acc[c]);
  unsigned short* op = o + ((size_t)b * HW + p) * 192 + h * 24;
  #pragma unroll
  for (int i = 0; i < 3; ++i) *(uint4*)(op + i * 8) = *(const uint4*)(ob + i * 8);
}

extern "C" void kernel_launch(void* const* d_in, const int* in_sizes, int n_in,
                              void* d_out, int out_size, void* d_ws, size_t ws_size,
                              hipStream_t stream){
  (void)in_sizes; (void)n_in; (void)out_size; (void)ws_size;
  const float* x        = (const float*)d_in[0];
  const float* t_emb    = (const float*)d_in[1];
  const float* n1_w     = (const float*)d_in[2];
  const float* n1_b     = (const float*)d_in[3];
  const float* temp     = (const float*)d_in[4];
  const float* a_qkv_w  = (const float*)d_in[5];
  const float* a_qkv_b  = (const float*)d_in[6];
  const float* a_dw_w   = (const float*)d_in[7];
  const float* a_dw_b   = (const float*)d_in[8];
  const float* a_proj_w = (const float*)d_in[9];
  const float* a_proj_b = (const float*)d_in[10];
  const float* a_t_w    = (const float*)d_in[11];
  const float* a_t_b    = (const float*)d_in[12];
  const float* n2_w     = (const float*)d_in[13];
  const float* n2_b     = (const float*)d_in[14];
  const float* f_c1_w   = (const float*)d_in[15];
  const float* f_c1_b   = (const float*)d_in[16];
  const float* f_dw_w   = (const float*)d_in[17];
  const float* f_dw_b   = (const float*)d_in[18];
  const float* f_c2_w   = (const float*)d_in[19];
  const float* f_c2_b   = (const float*)d_in[20];
  const float* f_t_w    = (const float*)d_in[21];
  const float* f_t_b    = (const float*)d_in[22];
  float* out = (float*)d_out;
  char* ws = (char*)d_ws;

  // workspace layout (~229 MB, phase-overlapped)
  unsigned short* y_buf = (unsigned short*)(ws + 0);          // [b][p][192] 25.2MB
  unsigned short* qkv   = (unsigned short*)(ws + 25165824);   // [b][576][HW] 75.5MB (stage A)
  unsigned short* hbuf  = (unsigned short*)(ws + 25165824);   // [b][1020][HW] 133.7MB (stage B)
  unsigned short* qkvd  = (unsigned short*)(ws + 100663296);  // [b][576][HW] 75.5MB
  unsigned short* obuf  = (unsigned short*)(ws + 176160768);  // [b][p][192] 25.2MB
  unsigned short* gbuf  = (unsigned short*)(ws + 158859264);  // [b][510][HW] 66.8MB
  const size_t S = 225705984;
  float* mod_a = (float*)(ws + S);
  float* mod_f = (float*)(ws + S + 8192);
  float* qn    = (float*)(ws + S + 16384);
  float* kn    = (float*)(ws + S + 20480);
  float* part  = (float*)(ws + S + 24576);        // 2359296
  float* attn  = (float*)(ws + S + 2383872);      // 73728
  unsigned short* Wq  = (unsigned short*)(ws + S + 2457600);  // 576x192
  unsigned short* Wp  = (unsigned short*)(ws + S + 2678784);  // 192x192
  unsigned short* W1  = (unsigned short*)(ws + S + 2752512);  // 1020x192
  unsigned short* W2p = (unsigned short*)(ws + S + 3144192);  // 192x512 (padded)

  castw_k<<<dim3((110592 + 255) / 256), 256, 0, stream>>>(a_qkv_w, Wq, 110592);
  castw_k<<<dim3((36864 + 255) / 256), 256, 0, stream>>>(a_proj_w, Wp, 36864);
  castw_k<<<dim3((195840 + 255) / 256), 256, 0, stream>>>(f_c1_w, W1, 195840);
  castw_pad_k<<<dim3((98304 + 255) / 256), 256, 0, stream>>>(f_c2_w, W2p, 192, 510, 512);
  modk<<<dim3(3, 4, 2), 128, 0, stream>>>(t_emb, a_t_w, a_t_b, f_t_w, f_t_b, mod_a, mod_f);
  (void)hipMemsetAsync(qn, 0, 2 * 768 * sizeof(float), stream);  // qn+kn contiguous

  // ---- MDTA branch ----
  lnmod_k<<<dim3(64, 4), 256, 0, stream>>>(x, n1_w, n1_b, mod_a, y_buf);
  gemm_tn2<0><<<2304, 256, 0, stream>>>(Wq, y_buf, a_qkv_b, nullptr, qkv, 576, 192, 9, 0);
  dw3_k<<<dim3(2, 2304), 256, 0, stream>>>(qkv, a_dw_w, a_dw_b, qkvd, 576, qn, kn);
  qk_k<<<dim3(32, 32), 64, 0, stream>>>(qkvd, part);
  softmax_k<<<32, 64, 0, stream>>>(part, qn, kn, temp, attn);
  av_k<<<dim3(64, 32), 256, 0, stream>>>(attn, qkvd, obuf);
  gemm_tn2<0><<<768, 256, 0, stream>>>(Wp, obuf, a_proj_b, x, out, 192, 192, 3, 1); // out = x1

  // ---- GDFN branch ----
  lnmod_k<<<dim3(64, 4), 256, 0, stream>>>(out, n2_w, n2_b, mod_f, y_buf);
  gemm_tn2<0><<<4096, 256, 0, stream>>>(W1, y_buf, f_c1_b, nullptr, hbuf, 1020, 192, 16, 0);
  dwgate_k<<<dim3(2, 2040), 256, 0, stream>>>(hbuf, f_dw_w, f_dw_b, gbuf);
  gemm_tn2<510><<<768, 256, 0, stream>>>(W2p, gbuf, f_c2_b, out, out, 192, 512, 3, 1);
}